// Round 8
// baseline (207.440 us; speedup 1.0000x reference)
//
#include <hip/hip_runtime.h>

// Problem constants
#define T_DIM 512
#define N_DIM 32
#define C_DIM 5000
#define S_DIM 128
#define STRIDE_T (N_DIM * C_DIM)      // 160000 elements between time steps

// Compact layout: (N, T, CROW); slots 0..127 = target slots, 128 = blank, 129 = pad
#define CROW 130
#define MAPB 5008                     // bytes per class->slot map row (padded)

// Workspace layout (bytes)
#define OFF_LOSS 0
#define OFF_MAP 512
#define OFF_COMPACT (OFF_MAP + N_DIM * MAPB)       // 512 + 160256 = 160768 (16-aligned)
#define WS_NEED (OFF_COMPACT + (size_t)N_DIM * T_DIM * CROW * 4)

// Filter kernel geometry: each block owns a CONTIGUOUS run of float4 groups
#define C4 (C_DIM / 4)                // 1250 float4 per (t,n) row
#define TOTAL4 (T_DIM * N_DIM * C4)   // 20,480,000 float4
#define FNB 2048
#define FTH 256
#define GPB (TOTAL4 / FNB)            // 10,000 groups per block (160 KB contiguous)
#define NB 8                          // loads in flight per thread
#define KMAX 40                       // ceil(GPB / FTH)

// Scan kernel geometry
#define TC 64                         // time steps per LDS chunk
#define NCHUNK (T_DIM / TC)           // 8
#define CH2 (TC * (CROW / 2))         // 4160 float2 per chunk
#define NLOADERS 192                  // 3 loader waves
#define NLOADF2 22                    // ceil(4160 / 192)

#define NEGF (-1e30f)
#define LOG2E_F 1.4426950408889634f
#define LN2_F 0.6931471805599453f

__device__ __forceinline__ float fexp2(float x) {
#if __has_builtin(__builtin_amdgcn_exp2f)
    return __builtin_amdgcn_exp2f(x);
#else
    return exp2f(x);
#endif
}
__device__ __forceinline__ float flog2(float x) {
#if __has_builtin(__builtin_amdgcn_logf)
    return __builtin_amdgcn_logf(x);
#else
    return log2f(x);
#endif
}
__device__ __forceinline__ float lse2(float a, float b) {
    float m = fmaxf(a, b);
    return m + flog2(fexp2(a - m) + fexp2(b - m));
}
__device__ __forceinline__ float lse3(float a, float b, float c) {
    float m = fmaxf(a, fmaxf(b, c));   // -> v_max3_f32
    return m + flog2(fexp2(a - m) + fexp2(b - m) + fexp2(c - m));
}

// ---------------- map build: per n, class -> slot byte map (first occurrence wins) ----------------
__global__ __launch_bounds__(256, 1) void ctc_mapbuild_kernel(
        const int* __restrict__ tgt,         // (N, S)
        unsigned char* __restrict__ map)     // (N, MAPB)
{
    const int n = blockIdx.x;
    const int tid = threadIdx.x;
    __shared__ int sm[C_DIM];
    for (int i = tid; i < C_DIM; i += 256) sm[i] = 255;
    __syncthreads();
    if (tid < S_DIM) atomicMin(&sm[tgt[n * S_DIM + tid]], tid);   // first occurrence wins
    __syncthreads();
    if (tid == 0) sm[0] = 128;               // blank class -> slot 128
    __syncthreads();
    unsigned char* gm = map + n * MAPB;
    for (int i = tid; i < C_DIM; i += 256) gm[i] = (unsigned char)sm[i];
    if (tid < MAPB - C_DIM) gm[C_DIM + tid] = 255;   // pad
}

// ---------------- filter: block-contiguous float4 stream; global byte map; rare scatter ----------------
__global__ __launch_bounds__(FTH, 6) void ctc_filter_kernel(
        const float4* __restrict__ lp4,          // (T*N*C4)
        const unsigned char* __restrict__ map,   // (N, MAPB)
        float* __restrict__ compact)             // (N, T, CROW)
{
    const int base = blockIdx.x * GPB;
    const int limit = base + GPB - 1;
    const int tid = threadIdx.x;

#pragma unroll 1
    for (int kb = 0; kb < KMAX; kb += NB) {
        float4 v[NB];
        unsigned int m[NB];
        int off[NB];
        // 1) issue the 8 streaming lp loads back-to-back (4 KB apart -> same DRAM row region)
#pragma unroll
        for (int j = 0; j < NB; ++j) {
            int g = base + tid + (kb + j) * FTH;
            if (g > limit) g = limit;            // clamped duplicate (idempotent)
            v[j] = lp4[g];
        }
        // 2) issue the 8 map dwords (L2-resident) + compute scatter bases
#pragma unroll
        for (int j = 0; j < NB; ++j) {
            int g = base + tid + (kb + j) * FTH;
            if (g > limit) g = limit;
            const int q = g / C4;                // q = t*N + n
            const int i = g - q * C4;
            const int n = q & (N_DIM - 1);
            const int t = q >> 5;
            m[j] = *(const unsigned int*)(map + n * MAPB + i * 4);
            off[j] = ((n << 9) + t) * CROW;      // (n*T + t)*CROW
        }
        // 3) rare scatter
#pragma unroll
        for (int j = 0; j < NB; ++j) {
            const unsigned int mm = m[j];
            if (mm != 0xFFFFFFFFu) {
                float* crow = compact + off[j];
                const unsigned s0 = mm & 255u, s1 = (mm >> 8) & 255u;
                const unsigned s2 = (mm >> 16) & 255u, s3 = mm >> 24;
                if (s0 != 255u) crow[s0] = v[j].x;
                if (s1 != 255u) crow[s1] = v[j].y;
                if (s2 != 255u) crow[s2] = v[j].z;
                if (s3 != 255u) crow[s3] = v[j].w;
            }
        }
    }
}

// ---------------- scan: one block (4 waves) per batch element ----------------
// Wave 0: sequential CTC alpha recurrence out of LDS.
// Waves 1-3: stream next chunk (contiguous 33 KB) from compact into LDS.
__global__ __launch_bounds__(256, 1) void ctc_scan_kernel(
        const float* __restrict__ compact, // (N, T, CROW)
        const int* __restrict__ tgt,       // (N, S)
        const int* __restrict__ il, const int* __restrict__ tl,
        float* __restrict__ loss_out)
{
    const int n = blockIdx.x;
    const int tid = threadIdx.x;
    const int wid = tid >> 6;
    const int lane = tid & 63;

    const int tlen = tl[n];
    const int ilen = il[n];
    const int* tgn = tgt + n * S_DIM;
    const float2* cbase2 = (const float2*)(compact + (size_t)n * T_DIM * CROW);

    __shared__ float buf[2][TC * CROW];
    __shared__ float sh[2];

    // prologue: loaders fill chunk 0 (contiguous stream)
    if (wid != 0) {
        const int ltid = tid - 64;
        float2* dst2 = (float2*)buf[0];
        float2 rg[NLOADF2];
#pragma unroll
        for (int j = 0; j < NLOADF2; ++j) {
            int i2 = ltid + NLOADERS * j; if (i2 >= CH2) i2 = CH2 - 1;
            rg[j] = cbase2[i2];
        }
#pragma unroll
        for (int j = 0; j < NLOADF2; ++j) {
            int i2 = ltid + NLOADERS * j; if (i2 >= CH2) i2 = CH2 - 1;
            dst2[i2] = rg[j];
        }
    }

    // scan setup (wave 0)
    int r1 = 0, r3 = 0;
    bool allow2_1 = false, allow2_3 = false;
    if (wid == 0) {
        const int c1i = 2 * lane, c3i = 2 * lane + 1;
        const int c1 = tgn[c1i];
        const int c3 = tgn[c3i];
        const int c1prev = (c1i > 0) ? tgn[c1i - 1] : -1;
        allow2_1 = (c1i > 0) && (c1 != c1prev);
        allow2_3 = (c3 != c1);
        // first-occurrence slot remap (duplicate-label-safe)
        r1 = c1i; r3 = c3i;
        for (int k = 0; k < S_DIM; ++k) {
            const int tk = tgn[k];
            if (tk == c1 && k < r1) r1 = k;
            if (tk == c3 && k < r3) r3 = k;
        }
        if (c1 == 0) r1 = 128;   // degenerate: blank used as target label
        if (c3 == 0) r3 = 128;
    }
    const int vmax = 2 * tlen;
    const int sb = lane << 2;
    const bool v0 = (sb    ) <= vmax;
    const bool v1 = (sb + 1) <= vmax;
    const bool v2 = (sb + 2) <= vmax;
    const bool v3 = (sb + 3) <= vmax;
    const bool v4 = (lane == 63) && (256 <= vmax);
    const int e1s = 2 * tlen;
    const int e2s = (2 * tlen - 1 > 0) ? (2 * tlen - 1) : 0;

    float a0 = NEGF, a1 = NEGF, a2 = NEGF, a3 = NEGF, a4 = NEGF;

    __syncthreads();   // chunk 0 ready

    for (int cc = 0; cc < NCHUNK; ++cc) {
        if (wid != 0) {
            if (cc + 1 < NCHUNK) {
                const int ltid = tid - 64;
                const float2* src2 = cbase2 + (size_t)(cc + 1) * CH2;
                float2* dst2 = (float2*)buf[(cc + 1) & 1];
                float2 rg[NLOADF2];
#pragma unroll
                for (int j = 0; j < NLOADF2; ++j) {
                    int i2 = ltid + NLOADERS * j; if (i2 >= CH2) i2 = CH2 - 1;
                    rg[j] = src2[i2];
                }
#pragma unroll
                for (int j = 0; j < NLOADF2; ++j) {
                    int i2 = ltid + NLOADERS * j; if (i2 >= CH2) i2 = CH2 - 1;
                    dst2[i2] = rg[j];
                }
            }
        } else {
            const float* lb = buf[cc & 1];
            float p1v = lb[r1], p3v = lb[r3], pbv = lb[128];
#pragma unroll 8
            for (int tt = 0; tt < TC; ++tt) {
                const int ttn = (tt + 1 < TC) ? (tt + 1) : tt;
                const float p1n = lb[ttn * CROW + r1];
                const float p3n = lb[ttn * CROW + r3];
                const float pbn = lb[ttn * CROW + 128];

                const int t = cc * TC + tt;
                const float pb = pbv * LOG2E_F;
                const float p1 = p1v * LOG2E_F;
                const float p3 = p3v * LOG2E_F;

                if (t == 0) {
                    a0 = (lane == 0) ? pb : NEGF;
                    a1 = (lane == 0 && tlen > 0) ? p1 : NEGF;
                    a2 = NEGF; a3 = NEGF; a4 = NEGF;
                    a0 = v0 ? a0 : NEGF;
                    a1 = v1 ? a1 : NEGF;
                } else {
                    float am1 = __shfl_up(a3, 1);   // alpha[4l-1] (old)
                    if (lane == 0) am1 = NEGF;

                    const float n0 = lse2(a0, am1);
                    const float n1 = allow2_1 ? lse3(a1, a0, am1) : lse2(a1, a0);
                    const float n2 = lse2(a2, a1);
                    const float n3 = allow2_3 ? lse3(a3, a2, a1) : lse2(a3, a2);
                    const float n4 = lse2(a4, a3);  // state 256 (lane 63)

                    a0 = v0 ? (n0 + pb) : NEGF;
                    a1 = v1 ? (n1 + p1) : NEGF;
                    a2 = v2 ? (n2 + pb) : NEGF;
                    a3 = v3 ? (n3 + p3) : NEGF;
                    a4 = v4 ? (n4 + pb) : NEGF;
                }

                if (t == ilen - 1) {
                    if (sb     == e1s) sh[0] = a0;
                    if (sb + 1 == e1s) sh[0] = a1;
                    if (sb + 2 == e1s) sh[0] = a2;
                    if (sb + 3 == e1s) sh[0] = a3;
                    if (lane == 63 && e1s == 256) sh[0] = a4;
                    if (sb     == e2s) sh[1] = a0;
                    if (sb + 1 == e2s) sh[1] = a1;
                    if (sb + 2 == e2s) sh[1] = a2;
                    if (sb + 3 == e2s) sh[1] = a3;
                }
                p1v = p1n; p3v = p3n; pbv = pbn;
            }
        }
        __syncthreads();
    }

    if (tid == 0) {
        const float e1 = sh[0];
        const float e2 = (tlen > 0) ? sh[1] : NEGF;
        const float m = fmaxf(e1, e2);
        const float ll2 = m + flog2(fexp2(e1 - m) + fexp2(e2 - m));
        float loss = -(ll2 * LN2_F);
        if (loss >= 1e29f) loss = 0.f;
        const int denom = (tlen > 1) ? tlen : 1;
        loss_out[n] = loss / (float)denom;
    }
}

// ---------------- fallback fused kernel (round-2 structure) if ws too small ----------------
#define FLDW 132
#define FNLOADERS 192
#define FNLOAD ((TC * 129) / FNLOADERS)   // 43

__global__ __launch_bounds__(256, 1) void ctc_fused_kernel(
        const float* __restrict__ lp, const int* __restrict__ tgt,
        const int* __restrict__ il, const int* __restrict__ tl,
        float* __restrict__ loss_out)
{
    const int n = blockIdx.x;
    const int tid = threadIdx.x;
    const int wid = tid >> 6;
    const int lane = tid & 63;
    const int tlen = tl[n];
    const int ilen = il[n];
    const int* tgn = tgt + n * S_DIM;
    const float* base = lp + (size_t)n * C_DIM;
    __shared__ float buf[2][TC * FLDW];
    __shared__ float sh[2];
    int gof[FNLOAD]; int wo[FNLOAD];
    if (wid != 0) {
        const int ltid = tid - 64;
#pragma unroll
        for (int j = 0; j < FNLOAD; ++j) {
            const int i = ltid + FNLOADERS * j;
            const int t = i / 129;
            const int k = i - 129 * t;
            const int cls = (k < 128) ? tgn[k] : 0;
            gof[j] = t * STRIDE_T + cls;
            wo[j] = t * FLDW + k;
        }
        float rg[FNLOAD];
#pragma unroll
        for (int j = 0; j < FNLOAD; ++j) rg[j] = base[(size_t)gof[j]];
#pragma unroll
        for (int j = 0; j < FNLOAD; ++j) buf[0][wo[j]] = rg[j];
    }
    const int c1i = 2 * lane, c3i = 2 * lane + 1;
    bool allow2_1 = false, allow2_3 = false;
    if (wid == 0) {
        const int c1 = tgn[c1i];
        const int c3 = tgn[c3i];
        const int c1prev = (c1i > 0) ? tgn[c1i - 1] : -1;
        allow2_1 = (c1i > 0) && (c1 != c1prev);
        allow2_3 = (c3 != c1);
    }
    const int vmax = 2 * tlen;
    const int sb = lane << 2;
    const bool v0 = (sb) <= vmax, v1 = (sb+1) <= vmax, v2 = (sb+2) <= vmax, v3 = (sb+3) <= vmax;
    const bool v4 = (lane == 63) && (256 <= vmax);
    const int e1s = 2 * tlen;
    const int e2s = (2 * tlen - 1 > 0) ? (2 * tlen - 1) : 0;
    float a0 = NEGF, a1 = NEGF, a2 = NEGF, a3 = NEGF, a4 = NEGF;
    __syncthreads();
    for (int cc = 0; cc < NCHUNK; ++cc) {
        if (wid != 0) {
            if (cc + 1 < NCHUNK) {
                const float* bp = base + (size_t)(cc + 1) * TC * STRIDE_T;
                float* dst = buf[(cc + 1) & 1];
                float rg[FNLOAD];
#pragma unroll
                for (int j = 0; j < FNLOAD; ++j) rg[j] = bp[(size_t)gof[j]];
#pragma unroll
                for (int j = 0; j < FNLOAD; ++j) dst[wo[j]] = rg[j];
            }
        } else {
            const float* lb = buf[cc & 1];
            float2 pq = *(const float2*)&lb[0 * FLDW + 2 * lane];
            float pbv = lb[0 * FLDW + 128];
#pragma unroll 8
            for (int tt = 0; tt < TC; ++tt) {
                const int ttn = (tt + 1 < TC) ? (tt + 1) : tt;
                const float2 pq_n = *(const float2*)&lb[ttn * FLDW + 2 * lane];
                const float pbv_n = lb[ttn * FLDW + 128];
                const int t = cc * TC + tt;
                const float pb = pbv * LOG2E_F, p1 = pq.x * LOG2E_F, p3 = pq.y * LOG2E_F;
                if (t == 0) {
                    a0 = (lane == 0) ? pb : NEGF;
                    a1 = (lane == 0 && tlen > 0) ? p1 : NEGF;
                    a2 = NEGF; a3 = NEGF; a4 = NEGF;
                    a0 = v0 ? a0 : NEGF;
                    a1 = v1 ? a1 : NEGF;
                } else {
                    float am1 = __shfl_up(a3, 1);
                    if (lane == 0) am1 = NEGF;
                    const float n0 = lse2(a0, am1);
                    const float n1 = allow2_1 ? lse3(a1, a0, am1) : lse2(a1, a0);
                    const float n2 = lse2(a2, a1);
                    const float n3 = allow2_3 ? lse3(a3, a2, a1) : lse2(a3, a2);
                    const float n4 = lse2(a4, a3);
                    a0 = v0 ? (n0 + pb) : NEGF;
                    a1 = v1 ? (n1 + p1) : NEGF;
                    a2 = v2 ? (n2 + pb) : NEGF;
                    a3 = v3 ? (n3 + p3) : NEGF;
                    a4 = v4 ? (n4 + pb) : NEGF;
                }
                if (t == ilen - 1) {
                    if (sb     == e1s) sh[0] = a0;
                    if (sb + 1 == e1s) sh[0] = a1;
                    if (sb + 2 == e1s) sh[0] = a2;
                    if (sb + 3 == e1s) sh[0] = a3;
                    if (lane == 63 && e1s == 256) sh[0] = a4;
                    if (sb     == e2s) sh[1] = a0;
                    if (sb + 1 == e2s) sh[1] = a1;
                    if (sb + 2 == e2s) sh[1] = a2;
                    if (sb + 3 == e2s) sh[1] = a3;
                }
                pq = pq_n; pbv = pbv_n;
            }
        }
        __syncthreads();
    }
    if (tid == 0) {
        const float e1 = sh[0];
        const float e2 = (tlen > 0) ? sh[1] : NEGF;
        const float m = fmaxf(e1, e2);
        const float ll2 = m + flog2(fexp2(e1 - m) + fexp2(e2 - m));
        float loss = -(ll2 * LN2_F);
        if (loss >= 1e29f) loss = 0.f;
        const int denom = (tlen > 1) ? tlen : 1;
        loss_out[n] = loss / (float)denom;
    }
}

__global__ __launch_bounds__(64, 1) void ctc_reduce_kernel(
        const float* __restrict__ loss, float* __restrict__ out)
{
    const int lane = threadIdx.x;
    float v = (lane < N_DIM) ? loss[lane] : 0.f;
#pragma unroll
    for (int off = 32; off > 0; off >>= 1) v += __shfl_down(v, off);
    if (lane == 0) out[0] = v / (float)N_DIM;
}

extern "C" void kernel_launch(void* const* d_in, const int* in_sizes, int n_in,
                              void* d_out, int out_size, void* d_ws, size_t ws_size,
                              hipStream_t stream) {
    const float* lp = (const float*)d_in[0];
    const int* tgt = (const int*)d_in[1];
    const int* il = (const int*)d_in[2];
    const int* tl = (const int*)d_in[3];
    float* out = (float*)d_out;

    float* losses = (float*)((char*)d_ws + OFF_LOSS);
    unsigned char* map = (unsigned char*)d_ws + OFF_MAP;
    float* compact = (float*)((char*)d_ws + OFF_COMPACT);

    if (ws_size >= WS_NEED) {
        ctc_mapbuild_kernel<<<N_DIM, 256, 0, stream>>>(tgt, map);
        ctc_filter_kernel<<<FNB, FTH, 0, stream>>>((const float4*)lp, map, compact);
        ctc_scan_kernel<<<N_DIM, 256, 0, stream>>>(compact, tgt, il, tl, losses);
    } else {
        ctc_fused_kernel<<<N_DIM, 256, 0, stream>>>(lp, tgt, il, tl, losses);
    }
    ctc_reduce_kernel<<<1, 64, 0, stream>>>(losses, out);
}

// Round 9
// 192.850 us; speedup vs baseline: 1.0757x; 1.0757x over previous
//
#include <hip/hip_runtime.h>

// Problem constants
#define T_DIM 512
#define N_DIM 32
#define C_DIM 5000
#define S_DIM 128
#define STRIDE_T (N_DIM * C_DIM)      // 160000 elements between time steps

// Compact layout: (N, T, CROW); slots 0..127 = target slots, 128 = blank, 129 = pad
#define CROW 130
#define MAPB 5008                     // bytes per class->slot map row (padded, 16-aligned)

// Workspace layout (bytes)
#define OFF_LOSS 0
#define OFF_MAP 512
#define OFF_COMPACT (OFF_MAP + N_DIM * MAPB)       // 512 + 160256 = 160768 (16-aligned)
#define WS_NEED (OFF_COMPACT + (size_t)N_DIM * T_DIM * CROW * 4)

// Filter kernel geometry: block owns FR rows (same n, consecutive t)
#define C4 (C_DIM / 4)                // 1250 float4 per row
#define FR 8                          // rows per block
#define FBLK (N_DIM * (T_DIM / FR))   // 2048 blocks
#define NBF 5                         // ceil(1250/256) float4 per thread per row

// Scan kernel geometry
#define TC 64                         // time steps per LDS chunk
#define NCHUNK (T_DIM / TC)           // 8
#define CH2 (TC * (CROW / 2))         // 4160 float2 per chunk
#define NLOADERS 192                  // 3 loader waves
#define NLOADF2 22                    // ceil(4160 / 192)

#define NEGF (-1e30f)
#define LOG2E_F 1.4426950408889634f
#define LN2_F 0.6931471805599453f

__device__ __forceinline__ float fexp2(float x) {
#if __has_builtin(__builtin_amdgcn_exp2f)
    return __builtin_amdgcn_exp2f(x);
#else
    return exp2f(x);
#endif
}
__device__ __forceinline__ float flog2(float x) {
#if __has_builtin(__builtin_amdgcn_logf)
    return __builtin_amdgcn_logf(x);
#else
    return log2f(x);
#endif
}
__device__ __forceinline__ float lse2(float a, float b) {
    float m = fmaxf(a, b);
    return m + flog2(fexp2(a - m) + fexp2(b - m));
}
__device__ __forceinline__ float lse3(float a, float b, float c) {
    float m = fmaxf(a, fmaxf(b, c));   // -> v_max3_f32
    return m + flog2(fexp2(a - m) + fexp2(b - m) + fexp2(c - m));
}

// ---------------- map build: per n, class -> slot byte map (first occurrence wins) ----------------
__global__ __launch_bounds__(256, 1) void ctc_mapbuild_kernel(
        const int* __restrict__ tgt,         // (N, S)
        unsigned char* __restrict__ map)     // (N, MAPB)
{
    const int n = blockIdx.x;
    const int tid = threadIdx.x;
    __shared__ int sm[C_DIM];
    for (int i = tid; i < C_DIM; i += 256) sm[i] = 255;
    __syncthreads();
    if (tid < S_DIM) atomicMin(&sm[tgt[n * S_DIM + tid]], tid);   // first occurrence wins
    __syncthreads();
    if (tid == 0) sm[0] = 128;               // blank class -> slot 128
    __syncthreads();
    unsigned char* gm = map + n * MAPB;
    for (int i = tid; i < C_DIM; i += 256) gm[i] = (unsigned char)sm[i];
    if (tid < MAPB - C_DIM) gm[C_DIM + tid] = 255;   // pad
}

// ---------------- filter v4: m13-shaped stream; LDS rowbuf; coalesced row writeout ----------------
// No scattered global stores, no per-row map lookups (row-invariant, hoisted),
// double-buffered register loads, 8 blocks/CU.
__global__ __launch_bounds__(256, 8) void ctc_filter_kernel(
        const float4* __restrict__ lp4,          // (T*N*C4)
        const unsigned char* __restrict__ map,   // (N, MAPB)
        float* __restrict__ compact)             // (N, T, CROW)
{
    const int bid = blockIdx.x;
    const int n = bid >> 6;             // 64 blocks per n
    const int tbase = (bid & 63) * FR;  // 8 consecutive t per block
    const int tid = threadIdx.x;

    __shared__ __align__(16) unsigned int smap[MAPB / 4];  // 1252 dwords (byte map)
    __shared__ float rbuf[2][136];

    const unsigned int* gmap = (const unsigned int*)(map + n * MAPB);
    for (int i = tid; i < MAPB / 4; i += 256) smap[i] = gmap[i];
    __syncthreads();

    // row-invariant per-thread map dwords (group j -> classes 4g..4g+3)
    unsigned int m[NBF];
    const bool act4 = (tid + 4 * 256) < C4;     // only j=4 can be inactive
#pragma unroll
    for (int j = 0; j < NBF; ++j) {
        int gg = tid + j * 256;
        if (gg >= C4) gg = C4 - 1;
        m[j] = smap[gg];
    }

    float4 v[2][NBF];
    const size_t rstride = STRIDE_T / 4;        // 40000 float4 between rows (t-major)
    const float4* rp0 = lp4 + (size_t)tbase * rstride + n * C4;
    // prologue: load row 0
#pragma unroll
    for (int j = 0; j < NBF; ++j) {
        int gg = tid + j * 256; if (gg >= C4) gg = C4 - 1;
        v[0][j] = rp0[gg];
    }

#pragma unroll
    for (int r = 0; r < FR; ++r) {
        const int cur = r & 1, nxt = cur ^ 1;
        // issue next row's loads (overwrites the buffer written out at r-1)
        if (r + 1 < FR) {
            const float4* rp = lp4 + (size_t)(tbase + r + 1) * rstride + n * C4;
#pragma unroll
            for (int j = 0; j < NBF; ++j) {
                int gg = tid + j * 256; if (gg >= C4) gg = C4 - 1;
                v[nxt][j] = rp[gg];
            }
        }
        // scatter current row's hits into LDS row buffer (rare)
#pragma unroll
        for (int j = 0; j < NBF; ++j) {
            const unsigned int mm = m[j];
            if ((j < NBF - 1 || act4) && mm != 0xFFFFFFFFu) {
                const unsigned s0 = mm & 255u, s1 = (mm >> 8) & 255u;
                const unsigned s2 = (mm >> 16) & 255u, s3 = mm >> 24;
                if (s0 != 255u) rbuf[cur][s0] = v[cur][j].x;
                if (s1 != 255u) rbuf[cur][s1] = v[cur][j].y;
                if (s2 != 255u) rbuf[cur][s2] = v[cur][j].z;
                if (s3 != 255u) rbuf[cur][s3] = v[cur][j].w;
            }
        }
        __syncthreads();
        // coalesced writeout of the 129 live slots
        if (tid < 129) {
            float* crow = compact + ((size_t)(n << 9) + (tbase + r)) * CROW;
            crow[tid] = rbuf[cur][tid];
        }
        // rbuf[nxt] reuse is protected by this iteration's barrier (writeout(r-1)
        // happened before it; scatter(r+1) happens after it)
    }
}

// ---------------- scan: one block (4 waves) per batch element ----------------
__global__ __launch_bounds__(256, 1) void ctc_scan_kernel(
        const float* __restrict__ compact, // (N, T, CROW)
        const int* __restrict__ tgt,       // (N, S)
        const int* __restrict__ il, const int* __restrict__ tl,
        float* __restrict__ loss_out)
{
    const int n = blockIdx.x;
    const int tid = threadIdx.x;
    const int wid = tid >> 6;
    const int lane = tid & 63;

    const int tlen = tl[n];
    const int ilen = il[n];
    const int* tgn = tgt + n * S_DIM;
    const float2* cbase2 = (const float2*)(compact + (size_t)n * T_DIM * CROW);

    __shared__ float buf[2][TC * CROW];
    __shared__ float sh[2];

    // prologue: loaders fill chunk 0 (contiguous stream)
    if (wid != 0) {
        const int ltid = tid - 64;
        float2* dst2 = (float2*)buf[0];
        float2 rg[NLOADF2];
#pragma unroll
        for (int j = 0; j < NLOADF2; ++j) {
            int i2 = ltid + NLOADERS * j; if (i2 >= CH2) i2 = CH2 - 1;
            rg[j] = cbase2[i2];
        }
#pragma unroll
        for (int j = 0; j < NLOADF2; ++j) {
            int i2 = ltid + NLOADERS * j; if (i2 >= CH2) i2 = CH2 - 1;
            dst2[i2] = rg[j];
        }
    }

    // scan setup (wave 0)
    int r1 = 0, r3 = 0;
    bool allow2_1 = false, allow2_3 = false;
    if (wid == 0) {
        const int c1i = 2 * lane, c3i = 2 * lane + 1;
        const int c1 = tgn[c1i];
        const int c3 = tgn[c3i];
        const int c1prev = (c1i > 0) ? tgn[c1i - 1] : -1;
        allow2_1 = (c1i > 0) && (c1 != c1prev);
        allow2_3 = (c3 != c1);
        // first-occurrence slot remap (duplicate-label-safe)
        r1 = c1i; r3 = c3i;
        for (int k = 0; k < S_DIM; ++k) {
            const int tk = tgn[k];
            if (tk == c1 && k < r1) r1 = k;
            if (tk == c3 && k < r3) r3 = k;
        }
        if (c1 == 0) r1 = 128;   // degenerate: blank used as target label
        if (c3 == 0) r3 = 128;
    }
    const int vmax = 2 * tlen;
    const int sb = lane << 2;
    const bool v0 = (sb    ) <= vmax;
    const bool v1 = (sb + 1) <= vmax;
    const bool v2 = (sb + 2) <= vmax;
    const bool v3 = (sb + 3) <= vmax;
    const bool v4 = (lane == 63) && (256 <= vmax);
    const int e1s = 2 * tlen;
    const int e2s = (2 * tlen - 1 > 0) ? (2 * tlen - 1) : 0;

    float a0 = NEGF, a1 = NEGF, a2 = NEGF, a3 = NEGF, a4 = NEGF;

    __syncthreads();   // chunk 0 ready

    for (int cc = 0; cc < NCHUNK; ++cc) {
        if (wid != 0) {
            if (cc + 1 < NCHUNK) {
                const int ltid = tid - 64;
                const float2* src2 = cbase2 + (size_t)(cc + 1) * CH2;
                float2* dst2 = (float2*)buf[(cc + 1) & 1];
                float2 rg[NLOADF2];
#pragma unroll
                for (int j = 0; j < NLOADF2; ++j) {
                    int i2 = ltid + NLOADERS * j; if (i2 >= CH2) i2 = CH2 - 1;
                    rg[j] = src2[i2];
                }
#pragma unroll
                for (int j = 0; j < NLOADF2; ++j) {
                    int i2 = ltid + NLOADERS * j; if (i2 >= CH2) i2 = CH2 - 1;
                    dst2[i2] = rg[j];
                }
            }
        } else {
            const float* lb = buf[cc & 1];
            float p1v = lb[r1], p3v = lb[r3], pbv = lb[128];
#pragma unroll 8
            for (int tt = 0; tt < TC; ++tt) {
                const int ttn = (tt + 1 < TC) ? (tt + 1) : tt;
                const float p1n = lb[ttn * CROW + r1];
                const float p3n = lb[ttn * CROW + r3];
                const float pbn = lb[ttn * CROW + 128];

                const int t = cc * TC + tt;
                const float pb = pbv * LOG2E_F;
                const float p1 = p1v * LOG2E_F;
                const float p3 = p3v * LOG2E_F;

                if (t == 0) {
                    a0 = (lane == 0) ? pb : NEGF;
                    a1 = (lane == 0 && tlen > 0) ? p1 : NEGF;
                    a2 = NEGF; a3 = NEGF; a4 = NEGF;
                    a0 = v0 ? a0 : NEGF;
                    a1 = v1 ? a1 : NEGF;
                } else {
                    float am1 = __shfl_up(a3, 1);   // alpha[4l-1] (old)
                    if (lane == 0) am1 = NEGF;

                    const float n0 = lse2(a0, am1);
                    const float n1 = allow2_1 ? lse3(a1, a0, am1) : lse2(a1, a0);
                    const float n2 = lse2(a2, a1);
                    const float n3 = allow2_3 ? lse3(a3, a2, a1) : lse2(a3, a2);
                    const float n4 = lse2(a4, a3);  // state 256 (lane 63)

                    a0 = v0 ? (n0 + pb) : NEGF;
                    a1 = v1 ? (n1 + p1) : NEGF;
                    a2 = v2 ? (n2 + pb) : NEGF;
                    a3 = v3 ? (n3 + p3) : NEGF;
                    a4 = v4 ? (n4 + pb) : NEGF;
                }

                if (t == ilen - 1) {
                    if (sb     == e1s) sh[0] = a0;
                    if (sb + 1 == e1s) sh[0] = a1;
                    if (sb + 2 == e1s) sh[0] = a2;
                    if (sb + 3 == e1s) sh[0] = a3;
                    if (lane == 63 && e1s == 256) sh[0] = a4;
                    if (sb     == e2s) sh[1] = a0;
                    if (sb + 1 == e2s) sh[1] = a1;
                    if (sb + 2 == e2s) sh[1] = a2;
                    if (sb + 3 == e2s) sh[1] = a3;
                }
                p1v = p1n; p3v = p3n; pbv = pbn;
            }
        }
        __syncthreads();
    }

    if (tid == 0) {
        const float e1 = sh[0];
        const float e2 = (tlen > 0) ? sh[1] : NEGF;
        const float m = fmaxf(e1, e2);
        const float ll2 = m + flog2(fexp2(e1 - m) + fexp2(e2 - m));
        float loss = -(ll2 * LN2_F);
        if (loss >= 1e29f) loss = 0.f;
        const int denom = (tlen > 1) ? tlen : 1;
        loss_out[n] = loss / (float)denom;
    }
}

// ---------------- fallback fused kernel (round-2 structure) if ws too small ----------------
#define FLDW 132
#define FNLOADERS 192
#define FNLOAD ((TC * 129) / FNLOADERS)   // 43

__global__ __launch_bounds__(256, 1) void ctc_fused_kernel(
        const float* __restrict__ lp, const int* __restrict__ tgt,
        const int* __restrict__ il, const int* __restrict__ tl,
        float* __restrict__ loss_out)
{
    const int n = blockIdx.x;
    const int tid = threadIdx.x;
    const int wid = tid >> 6;
    const int lane = tid & 63;
    const int tlen = tl[n];
    const int ilen = il[n];
    const int* tgn = tgt + n * S_DIM;
    const float* base = lp + (size_t)n * C_DIM;
    __shared__ float buf[2][TC * FLDW];
    __shared__ float sh[2];
    int gof[FNLOAD]; int wo[FNLOAD];
    if (wid != 0) {
        const int ltid = tid - 64;
#pragma unroll
        for (int j = 0; j < FNLOAD; ++j) {
            const int i = ltid + FNLOADERS * j;
            const int t = i / 129;
            const int k = i - 129 * t;
            const int cls = (k < 128) ? tgn[k] : 0;
            gof[j] = t * STRIDE_T + cls;
            wo[j] = t * FLDW + k;
        }
        float rg[FNLOAD];
#pragma unroll
        for (int j = 0; j < FNLOAD; ++j) rg[j] = base[(size_t)gof[j]];
#pragma unroll
        for (int j = 0; j < FNLOAD; ++j) buf[0][wo[j]] = rg[j];
    }
    const int c1i = 2 * lane, c3i = 2 * lane + 1;
    bool allow2_1 = false, allow2_3 = false;
    if (wid == 0) {
        const int c1 = tgn[c1i];
        const int c3 = tgn[c3i];
        const int c1prev = (c1i > 0) ? tgn[c1i - 1] : -1;
        allow2_1 = (c1i > 0) && (c1 != c1prev);
        allow2_3 = (c3 != c1);
    }
    const int vmax = 2 * tlen;
    const int sb = lane << 2;
    const bool v0 = (sb) <= vmax, v1 = (sb+1) <= vmax, v2 = (sb+2) <= vmax, v3 = (sb+3) <= vmax;
    const bool v4 = (lane == 63) && (256 <= vmax);
    const int e1s = 2 * tlen;
    const int e2s = (2 * tlen - 1 > 0) ? (2 * tlen - 1) : 0;
    float a0 = NEGF, a1 = NEGF, a2 = NEGF, a3 = NEGF, a4 = NEGF;
    __syncthreads();
    for (int cc = 0; cc < NCHUNK; ++cc) {
        if (wid != 0) {
            if (cc + 1 < NCHUNK) {
                const float* bp = base + (size_t)(cc + 1) * TC * STRIDE_T;
                float* dst = buf[(cc + 1) & 1];
                float rg[FNLOAD];
#pragma unroll
                for (int j = 0; j < FNLOAD; ++j) rg[j] = bp[(size_t)gof[j]];
#pragma unroll
                for (int j = 0; j < FNLOAD; ++j) dst[wo[j]] = rg[j];
            }
        } else {
            const float* lb = buf[cc & 1];
            float2 pq = *(const float2*)&lb[0 * FLDW + 2 * lane];
            float pbv = lb[0 * FLDW + 128];
#pragma unroll 8
            for (int tt = 0; tt < TC; ++tt) {
                const int ttn = (tt + 1 < TC) ? (tt + 1) : tt;
                const float2 pq_n = *(const float2*)&lb[ttn * FLDW + 2 * lane];
                const float pbv_n = lb[ttn * FLDW + 128];
                const int t = cc * TC + tt;
                const float pb = pbv * LOG2E_F, p1 = pq.x * LOG2E_F, p3 = pq.y * LOG2E_F;
                if (t == 0) {
                    a0 = (lane == 0) ? pb : NEGF;
                    a1 = (lane == 0 && tlen > 0) ? p1 : NEGF;
                    a2 = NEGF; a3 = NEGF; a4 = NEGF;
                    a0 = v0 ? a0 : NEGF;
                    a1 = v1 ? a1 : NEGF;
                } else {
                    float am1 = __shfl_up(a3, 1);
                    if (lane == 0) am1 = NEGF;
                    const float n0 = lse2(a0, am1);
                    const float n1 = allow2_1 ? lse3(a1, a0, am1) : lse2(a1, a0);
                    const float n2 = lse2(a2, a1);
                    const float n3 = allow2_3 ? lse3(a3, a2, a1) : lse2(a3, a2);
                    const float n4 = lse2(a4, a3);
                    a0 = v0 ? (n0 + pb) : NEGF;
                    a1 = v1 ? (n1 + p1) : NEGF;
                    a2 = v2 ? (n2 + pb) : NEGF;
                    a3 = v3 ? (n3 + p3) : NEGF;
                    a4 = v4 ? (n4 + pb) : NEGF;
                }
                if (t == ilen - 1) {
                    if (sb     == e1s) sh[0] = a0;
                    if (sb + 1 == e1s) sh[0] = a1;
                    if (sb + 2 == e1s) sh[0] = a2;
                    if (sb + 3 == e1s) sh[0] = a3;
                    if (lane == 63 && e1s == 256) sh[0] = a4;
                    if (sb     == e2s) sh[1] = a0;
                    if (sb + 1 == e2s) sh[1] = a1;
                    if (sb + 2 == e2s) sh[1] = a2;
                    if (sb + 3 == e2s) sh[1] = a3;
                }
                pq = pq_n; pbv = pbv_n;
            }
        }
        __syncthreads();
    }
    if (tid == 0) {
        const float e1 = sh[0];
        const float e2 = (tlen > 0) ? sh[1] : NEGF;
        const float m = fmaxf(e1, e2);
        const float ll2 = m + flog2(fexp2(e1 - m) + fexp2(e2 - m));
        float loss = -(ll2 * LN2_F);
        if (loss >= 1e29f) loss = 0.f;
        const int denom = (tlen > 1) ? tlen : 1;
        loss_out[n] = loss / (float)denom;
    }
}

__global__ __launch_bounds__(64, 1) void ctc_reduce_kernel(
        const float* __restrict__ loss, float* __restrict__ out)
{
    const int lane = threadIdx.x;
    float v = (lane < N_DIM) ? loss[lane] : 0.f;
#pragma unroll
    for (int off = 32; off > 0; off >>= 1) v += __shfl_down(v, off);
    if (lane == 0) out[0] = v / (float)N_DIM;
}

extern "C" void kernel_launch(void* const* d_in, const int* in_sizes, int n_in,
                              void* d_out, int out_size, void* d_ws, size_t ws_size,
                              hipStream_t stream) {
    const float* lp = (const float*)d_in[0];
    const int* tgt = (const int*)d_in[1];
    const int* il = (const int*)d_in[2];
    const int* tl = (const int*)d_in[3];
    float* out = (float*)d_out;

    float* losses = (float*)((char*)d_ws + OFF_LOSS);
    unsigned char* map = (unsigned char*)d_ws + OFF_MAP;
    float* compact = (float*)((char*)d_ws + OFF_COMPACT);

    if (ws_size >= WS_NEED) {
        ctc_mapbuild_kernel<<<N_DIM, 256, 0, stream>>>(tgt, map);
        ctc_filter_kernel<<<FBLK, 256, 0, stream>>>((const float4*)lp, map, compact);
        ctc_scan_kernel<<<N_DIM, 256, 0, stream>>>(compact, tgt, il, tl, losses);
    } else {
        ctc_fused_kernel<<<N_DIM, 256, 0, stream>>>(lp, tgt, il, tl, losses);
    }
    ctc_reduce_kernel<<<1, 64, 0, stream>>>(losses, out);
}

// Round 10
// 138.336 us; speedup vs baseline: 1.4995x; 1.3941x over previous
//
#include <hip/hip_runtime.h>

// Problem constants
#define T_DIM 512
#define N_DIM 32
#define C_DIM 5000
#define S_DIM 128
#define STRIDE_T (N_DIM * C_DIM)      // 160000 elements between time steps

// Fused kernel geometry: 1 scan wave + 2 loader waves (one loader per slot column)
#define TC 64                          // time steps per LDS chunk
#define NCHUNK (T_DIM / TC)            // 8
#define FLDW 132                       // LDS row stride (slots 0..127 + pad)
#define LB 32                          // load batch depth per loader (2 batches per chunk)

#define NEGF (-1e30f)
#define LOG2E_F 1.4426950408889634f
#define LN2_F 0.6931471805599453f

__device__ __forceinline__ float fexp2(float x) {
#if __has_builtin(__builtin_amdgcn_exp2f)
    return __builtin_amdgcn_exp2f(x);
#else
    return exp2f(x);
#endif
}
__device__ __forceinline__ float flog2(float x) {
#if __has_builtin(__builtin_amdgcn_logf)
    return __builtin_amdgcn_logf(x);
#else
    return log2f(x);
#endif
}
__device__ __forceinline__ float lse2(float a, float b) {
    float m = fmaxf(a, b);
    return m + flog2(fexp2(a - m) + fexp2(b - m));
}
__device__ __forceinline__ float lse3(float a, float b, float c) {
    float m = fmaxf(a, fmaxf(b, c));   // -> v_max3_f32
    return m + flog2(fexp2(a - m) + fexp2(b - m) + fexp2(c - m));
}

// One block (3 waves) per batch element.
// Wave 0: sequential CTC alpha recurrence out of LDS (+ blank column via strided load + shfl).
// Waves 1-2: 128 loaders; loader k owns slot column k (cls in register, induction addressing,
//            32-deep independent load batches -> max memory-level parallelism).
__global__ __launch_bounds__(192, 1) void ctc_fused_kernel(
        const float* __restrict__ lp,   // (T, N, C)
        const int* __restrict__ tgt,    // (N, S)
        const int* __restrict__ il,     // (N,)
        const int* __restrict__ tl,     // (N,)
        float* __restrict__ loss_out)   // (N,)
{
    const int n = blockIdx.x;
    const int tid = threadIdx.x;
    const int wid = tid >> 6;
    const int lane = tid & 63;

    const int tlen = tl[n];
    const int ilen = il[n];
    const int* tgn = tgt + n * S_DIM;
    const float* base = lp + (size_t)n * C_DIM;

    __shared__ float buf[2][TC * FLDW];
    __shared__ float sh[2];

    // ---------------- loader setup + prologue: fill chunk 0 ----------------
    int cls = 0;
    if (wid != 0) {
        const int k = tid - 64;              // slot column 0..127 (per-slot gather: duplicate-safe)
        cls = tgn[k];
        const float* cb = base + cls;
#pragma unroll
        for (int b = 0; b < TC / LB; ++b) {
            float rg[LB];
#pragma unroll
            for (int j = 0; j < LB; ++j)
                rg[j] = cb[(size_t)(b * LB + j) * STRIDE_T];
#pragma unroll
            for (int j = 0; j < LB; ++j)
                buf[0][(b * LB + j) * FLDW + k] = rg[j];
        }
    }

    // ---------------- scan setup (wave 0) ----------------
    // lane l states: 4l (blank), 4l+1 (slot 2l), 4l+2 (blank), 4l+3 (slot 2l+1)
    float blankv = 0.f;
    bool allow2_1 = false, allow2_3 = false;
    if (wid == 0) {
        blankv = base[(size_t)lane * STRIDE_T];   // lp[t=lane][n][blank], chunk 0
        const int c1i = 2 * lane, c3i = 2 * lane + 1;
        const int c1 = tgn[c1i];
        const int c3 = tgn[c3i];
        const int c1prev = (c1i > 0) ? tgn[c1i - 1] : -1;
        allow2_1 = (c1i > 0) && (c1 != c1prev);
        allow2_3 = (c3 != c1);
    }
    const int vmax = 2 * tlen;
    const int sb = lane << 2;
    const bool v0 = (sb    ) <= vmax;
    const bool v1 = (sb + 1) <= vmax;
    const bool v2 = (sb + 2) <= vmax;
    const bool v3 = (sb + 3) <= vmax;
    const bool v4 = (lane == 63) && (256 <= vmax);
    const int e1s = 2 * tlen;
    const int e2s = (2 * tlen - 1 > 0) ? (2 * tlen - 1) : 0;

    float a0 = NEGF, a1 = NEGF, a2 = NEGF, a3 = NEGF, a4 = NEGF;

    __syncthreads();   // chunk 0 ready

    for (int cc = 0; cc < NCHUNK; ++cc) {
        if (wid != 0) {
            // fill chunk cc+1 into buf[(cc+1)&1]
            if (cc + 1 < NCHUNK) {
                const int k = tid - 64;
                const float* cb = base + (size_t)(cc + 1) * TC * STRIDE_T + cls;
                float* dst = buf[(cc + 1) & 1];
#pragma unroll
                for (int b = 0; b < TC / LB; ++b) {
                    float rg[LB];
#pragma unroll
                    for (int j = 0; j < LB; ++j)
                        rg[j] = cb[(size_t)(b * LB + j) * STRIDE_T];
#pragma unroll
                    for (int j = 0; j < LB; ++j)
                        dst[(b * LB + j) * FLDW + k] = rg[j];
                }
            }
        } else {
            const float* lb = buf[cc & 1];
            // prefetch next chunk's blank column (1 strided load, in flight across the chunk)
            float blankn = 0.f;
            if (cc + 1 < NCHUNK)
                blankn = base[((size_t)(cc + 1) * TC + lane) * STRIDE_T];

            // one-step software-pipelined reads (LDS float2 + blank shfl)
            float2 pq = *(const float2*)&lb[2 * lane];
            float pbv = __shfl(blankv, 0);
#pragma unroll 8
            for (int tt = 0; tt < TC; ++tt) {
                const int ttn = (tt + 1 < TC) ? (tt + 1) : tt;
                const float2 pq_n = *(const float2*)&lb[ttn * FLDW + 2 * lane];
                const float pbv_n = __shfl(blankv, ttn);

                const int t = cc * TC + tt;
                const float pb = pbv  * LOG2E_F;
                const float p1 = pq.x * LOG2E_F;
                const float p3 = pq.y * LOG2E_F;

                if (t == 0) {
                    a0 = (lane == 0) ? pb : NEGF;
                    a1 = (lane == 0 && tlen > 0) ? p1 : NEGF;
                    a2 = NEGF; a3 = NEGF; a4 = NEGF;
                    a0 = v0 ? a0 : NEGF;
                    a1 = v1 ? a1 : NEGF;
                } else {
                    float am1 = __shfl_up(a3, 1);   // alpha[4l-1] (old)
                    if (lane == 0) am1 = NEGF;

                    const float n0 = lse2(a0, am1);
                    const float n1 = allow2_1 ? lse3(a1, a0, am1) : lse2(a1, a0);
                    const float n2 = lse2(a2, a1);
                    const float n3 = allow2_3 ? lse3(a3, a2, a1) : lse2(a3, a2);
                    const float n4 = lse2(a4, a3);  // state 256 (lane 63)

                    a0 = v0 ? (n0 + pb) : NEGF;
                    a1 = v1 ? (n1 + p1) : NEGF;
                    a2 = v2 ? (n2 + pb) : NEGF;
                    a3 = v3 ? (n3 + p3) : NEGF;
                    a4 = v4 ? (n4 + pb) : NEGF;
                }

                if (t == ilen - 1) {
                    if (sb     == e1s) sh[0] = a0;
                    if (sb + 1 == e1s) sh[0] = a1;
                    if (sb + 2 == e1s) sh[0] = a2;
                    if (sb + 3 == e1s) sh[0] = a3;
                    if (lane == 63 && e1s == 256) sh[0] = a4;
                    if (sb     == e2s) sh[1] = a0;
                    if (sb + 1 == e2s) sh[1] = a1;
                    if (sb + 2 == e2s) sh[1] = a2;
                    if (sb + 3 == e2s) sh[1] = a3;
                }
                pq = pq_n; pbv = pbv_n;
            }
            blankv = blankn;
        }
        __syncthreads();
    }

    if (tid == 0) {
        const float e1 = sh[0];
        const float e2 = (tlen > 0) ? sh[1] : NEGF;
        const float m = fmaxf(e1, e2);
        const float ll2 = m + flog2(fexp2(e1 - m) + fexp2(e2 - m));
        float loss = -(ll2 * LN2_F);
        if (loss >= 1e29f) loss = 0.f;
        const int denom = (tlen > 1) ? tlen : 1;
        loss_out[n] = loss / (float)denom;
    }
}

__global__ __launch_bounds__(64, 1) void ctc_reduce_kernel(
        const float* __restrict__ loss, float* __restrict__ out)
{
    const int lane = threadIdx.x;
    float v = (lane < N_DIM) ? loss[lane] : 0.f;
#pragma unroll
    for (int off = 32; off > 0; off >>= 1) v += __shfl_down(v, off);
    if (lane == 0) out[0] = v / (float)N_DIM;
}

extern "C" void kernel_launch(void* const* d_in, const int* in_sizes, int n_in,
                              void* d_out, int out_size, void* d_ws, size_t ws_size,
                              hipStream_t stream) {
    const float* lp = (const float*)d_in[0];
    const int* tgt = (const int*)d_in[1];
    const int* il = (const int*)d_in[2];
    const int* tl = (const int*)d_in[3];
    float* out = (float*)d_out;
    float* losses = (float*)d_ws;

    ctc_fused_kernel<<<N_DIM, 192, 0, stream>>>(lp, tgt, il, tl, losses);
    ctc_reduce_kernel<<<1, 64, 0, stream>>>(losses, out);
}